// Round 12
// baseline (1013.085 us; speedup 1.0000x reference)
//
#include <hip/hip_runtime.h>

#define SS 8
#define NN 5000
#define NNSQ 25000000
#define DD 128
#define RB 4          // rows per block; waves pair up per row
#define JS 2          // column chunks (partials)
#define JC 2500       // chunk width
#define JT 256        // tile columns
#define TPB 10        // tiles per chunk (2560 >= 2500)
#define RG 1250       // row groups = NN/RB

typedef float f4 __attribute__((ext_vector_type(4)));

typedef const __attribute__((address_space(1))) void glb_void;
typedef __attribute__((address_space(3))) void lds_void;

// aux=2: slc/nt streaming hint -- T/a are read exactly once; keep them from
// evicting the hot x (2.56 MB) out of L2.
__device__ __forceinline__ void gld_lds16_nt(const void* g, void* l) {
    __builtin_amdgcn_global_load_lds((glb_void*)g, (lds_void*)l, 16, 0, 2);
}

#define VMCNT0 asm volatile("s_waitcnt vmcnt(0)" ::: "memory")
#define SB0    __builtin_amdgcn_sched_barrier(0)

// R5-proven schedule; 512-thread blocks (16 waves/CU), RB=4 x JT=256 tiles.
// Staging: wave w owns (row = w>>1, colhalf = w&1): 9 DMA instrs of 512 B,
// lanes 0..31 active; adjacent colhalves/tiles make runs contiguous in memory.
// qcompute stays own-wave -> single barrier per tile.
__global__ __launch_bounds__(512, 4)
void diffuse_spmm(const float* __restrict__ theta,
                  const float* __restrict__ Tm,
                  const float* __restrict__ x,
                  const float* __restrict__ am,
                  float* __restrict__ ws)
{
    __shared__ float stg[SS + 1][RB][JT];   // 36,864 B: slices 0..7 = T, 8 = a
    __shared__ float qv[2][RB][JT];         // 8,192 B double-buffered q tile

    const int t    = threadIdx.x;
    const int wid  = t >> 6;                // 0..7
    const int lane = t & 63;
    const int rg   = blockIdx.x % RG;
    const int js   = blockIdx.x / RG;
    const int i0   = rg * RB;
    const int jc   = js * JC;
    const int jend = jc + JC;               // chunk boundary (<= NN, exact here)

    // staging / qcompute mapping: wave wid -> (row, colhalf); lanes 0..31 active
    const int srow = wid >> 1;
    const int sch  = (wid & 1) << 7;        // 0 or 128
    const int scol = sch + ((lane & 31) << 2);
    const bool sact = (lane < 32);
    // Phase B mapping: 16 half-waves x 16 j each; d-quad per lane
    const int hw = t >> 5;                  // 0..15
    const int d0 = (t & 31) << 2;

    float th[SS];
#pragma unroll
    for (int s = 0; s < SS; ++s) th[s] = theta[s];

    // DMA tile k: 9 instrs/wave, 512 B each (lanes 0..31), streaming hint.
    auto stage_dma = [&](int k) {
        const int jg = jc + k * JT + scol;
        if (sact && jg < jend) {
            const size_t goff = (size_t)(i0 + srow) * NN + jg;
#pragma unroll
            for (int s = 0; s < SS; ++s)
                gld_lds16_nt(Tm + (size_t)s * NNSQ + goff, &stg[s][srow][sch]);
            gld_lds16_nt(am + goff, &stg[SS][srow][sch]);
        }
    };

    // q for tile k -> qv[n]; reads only own-wave staged (row, colhalf)
    auto qcompute = [&](int k, int n) {
        if (sact) {
            const int jg = jc + k * JT + scol;
            f4 ssum = (*(const f4*)&stg[0][srow][scol]) * th[0];
#pragma unroll
            for (int s = 1; s < SS; ++s)
                ssum += (*(const f4*)&stg[s][srow][scol]) * th[s];
            f4 q = (*(const f4*)&stg[SS][srow][scol]) * ssum;
            if (jg >= jend) q = (f4)(0.0f);  // ragged tile: zero stale cols
            *(f4*)&qv[n][srow][scol] = q;
        }
    };

    f4 acc[RB];
#pragma unroll
    for (int r = 0; r < RB; ++r) acc[r] = (f4)(0.0f);

    // prologue
    stage_dma(0);
    VMCNT0;
    SB0;
    qcompute(0, 0);
    __syncthreads();

#pragma unroll 1
    for (int k = 0; k < TPB; ++k) {
        // ---- x loads for THIS tile: FIRST into the vmcnt FIFO ----
        f4 xv[16];                           // static indexing only
        {
            const int jb = jc + k * JT + (hw << 4);
#pragma unroll
            for (int q = 0; q < 16; ++q) {
                const int j = jb + q;
                xv[q] = (j < jend) ? *(const f4*)(x + (size_t)j * DD + d0)
                                   : (f4)(0.0f);
            }
        }
        SB0;
        // ---- next tile's T/a DMA: LAST into the FIFO (0 registers) ----
        if (k + 1 < TPB) stage_dma(k + 1);
        SB0;

        // ---- Phase B: acc[r] += qv[r][jj] * x[jj][d0..d0+3] ----
        // consuming xv waits vmcnt<=9 at worst -> DMA stays in flight
        const float* qp = &qv[k & 1][0][0];
#pragma unroll
        for (int qc = 0; qc < 4; ++qc) {
#pragma unroll
            for (int r = 0; r < RB; ++r) {
                f4 q4 = *(const f4*)&qp[r * JT + (hw << 4) + (qc << 2)];
                acc[r] += q4.x * xv[qc * 4 + 0];
                acc[r] += q4.y * xv[qc * 4 + 1];
                acc[r] += q4.z * xv[qc * 4 + 2];
                acc[r] += q4.w * xv[qc * 4 + 3];
            }
        }

        if (k + 1 < TPB) {
            VMCNT0;                          // DMA issued ~2000 cyc ago (wall)
            SB0;
            qcompute(k + 1, (k + 1) & 1);    // own-wave -> no pre-barrier
            __syncthreads();                 // publish qv; orders stage reuse
        }
    }

    // ---- epilogue: fold half-wave j-groups, then cross-wave reduce ----
#pragma unroll
    for (int r = 0; r < RB; ++r)
#pragma unroll
        for (int c = 0; c < 4; ++c)
            acc[r][c] += __shfl_xor(acc[r][c], 32);

    __syncthreads();                         // loop done; stage dead -> alias
    float* red = (float*)&stg[0][0][0];      // 7 waves * 4 rows * 128 d = 14,336 B
    if (wid > 0 && lane < 32) {
#pragma unroll
        for (int r = 0; r < RB; ++r)
            *(f4*)&red[((wid - 1) * RB + r) * DD + d0] = acc[r];
    }
    __syncthreads();
    if (wid == 0 && lane < 32) {
#pragma unroll
        for (int r = 0; r < RB; ++r) {
            f4 v = acc[r];
#pragma unroll
            for (int p = 0; p < 7; ++p)
                v += *(const f4*)&red[(p * RB + r) * DD + d0];
            *(f4*)&ws[(((size_t)js * RG + rg) * RB + r) * DD + d0] = v;
        }
    }
}

// Kernel 2: out[i,:] = PReLU(sum_js partial[js][i,:]) @ W^T + b
__global__ __launch_bounds__(256, 2)
void prelu_linear(const float* __restrict__ alpha,
                  const float* __restrict__ W,
                  const float* __restrict__ b,
                  const float* __restrict__ ws,
                  float* __restrict__ out)
{
    __shared__ float Wt[128 * 129];
    __shared__ float p[16 * 128];
    const int t  = threadIdx.x;
    const int i0 = blockIdx.x * 16;

#pragma unroll
    for (int it = 0; it < 16; ++it) {
        int f  = (it * 256 + t) * 4;
        int d  = f >> 7;
        int kk = f & 127;
        f4 w4 = *(const f4*)(W + f);
        Wt[(kk + 0) * 129 + d] = w4.x;
        Wt[(kk + 1) * 129 + d] = w4.y;
        Wt[(kk + 2) * 129 + d] = w4.z;
        Wt[(kk + 3) * 129 + d] = w4.w;
    }

#pragma unroll
    for (int it = 0; it < 2; ++it) {
        int fi  = it * 256 + t;
        int row = i0 + (fi >> 5);
        int dc  = (fi & 31) << 2;
        if (row < NN) {
            size_t base = (size_t)row * DD + dc;
            f4 v = *(const f4*)(ws + base);
            v += *(const f4*)(ws + base + (size_t)RG * RB * DD);   // 2nd partial
            f4 al = *(const f4*)(alpha + dc);
            f4 pv;
            pv.x = v.x >= 0.f ? v.x : al.x * v.x;
            pv.y = v.y >= 0.f ? v.y : al.y * v.y;
            pv.z = v.z >= 0.f ? v.z : al.z * v.z;
            pv.w = v.w >= 0.f ? v.w : al.w * v.w;
            *(f4*)&p[(row - i0) * 128 + dc] = pv;
        }
    }
    __syncthreads();

    const int d  = t & 127;
    const int rq = t >> 7;
    const float bv = b[d];
    float acc[8];
#pragma unroll
    for (int ri = 0; ri < 8; ++ri) acc[ri] = 0.f;
#pragma unroll 8
    for (int k = 0; k < 128; ++k) {
        float wv = Wt[k * 129 + d];
#pragma unroll
        for (int ri = 0; ri < 8; ++ri)
            acc[ri] += p[(rq * 8 + ri) * 128 + k] * wv;
    }
#pragma unroll
    for (int ri = 0; ri < 8; ++ri) {
        int row = i0 + rq * 8 + ri;
        if (row < NN) out[(size_t)row * DD + d] = acc[ri] + bv;
    }
}

extern "C" void kernel_launch(void* const* d_in, const int* in_sizes, int n_in,
                              void* d_out, int out_size, void* d_ws, size_t ws_size,
                              hipStream_t stream) {
    const float* theta = (const float*)d_in[0];
    const float* T     = (const float*)d_in[1];
    const float* x     = (const float*)d_in[2];
    const float* a     = (const float*)d_in[3];
    const float* alpha = (const float*)d_in[4];
    const float* W     = (const float*)d_in[5];
    const float* b     = (const float*)d_in[6];
    float* out = (float*)d_out;
    float* ws  = (float*)d_ws;

    dim3 g1(RG * JS);                  // 2500 blocks x 512 threads
    diffuse_spmm<<<g1, dim3(512), 0, stream>>>(theta, T, x, a, ws);

    dim3 g2((NN + 15) / 16);           // 313 blocks
    prelu_linear<<<g2, dim3(256), 0, stream>>>(alpha, W, b, ws, out);
}

// Round 13
// 335.094 us; speedup vs baseline: 3.0233x; 3.0233x over previous
//
#include <hip/hip_runtime.h>

#define SS 8
#define NN 5000
#define NNSQ 25000000
#define DD 128
#define RB 4          // rows per block; waves pair up per row
#define JS 2          // column chunks (partials)
#define JC 2500       // chunk width
#define JT 256        // tile columns
#define TPB 10        // tiles per chunk (2560 >= 2500)
#define RG 1250       // row groups = NN/RB

typedef float f4 __attribute__((ext_vector_type(4)));

typedef const __attribute__((address_space(1))) void glb_void;
typedef __attribute__((address_space(3))) void lds_void;

// aux=2: slc/nt streaming hint -- T/a are read exactly once; keep them from
// evicting the hot x (2.56 MB) out of L2.
__device__ __forceinline__ void gld_lds16_nt(const void* g, void* l) {
    __builtin_amdgcn_global_load_lds((glb_void*)g, (lds_void*)l, 16, 0, 2);
}

#define VMCNT0 asm volatile("s_waitcnt vmcnt(0)" ::: "memory")
#define SB0    __builtin_amdgcn_sched_barrier(0)

// R5-proven schedule; 512-thread blocks (16 waves/CU), RB=4 x JT=256 tiles.
// __launch_bounds__(512, 2): empirical allocator law grants 512/(2*2) = 128
// VGPRs -- the budget proven spill-free for this body (R5/R11).
// Staging: wave w owns (row = w>>1, colhalf = w&1): 9 DMA instrs of 512 B,
// lanes 0..31 active. qcompute stays own-wave -> single barrier per tile.
__global__ __launch_bounds__(512, 2)
void diffuse_spmm(const float* __restrict__ theta,
                  const float* __restrict__ Tm,
                  const float* __restrict__ x,
                  const float* __restrict__ am,
                  float* __restrict__ ws)
{
    __shared__ float stg[SS + 1][RB][JT];   // 36,864 B: slices 0..7 = T, 8 = a
    __shared__ float qv[2][RB][JT];         // 8,192 B double-buffered q tile
    // total 45,056 B; 2 blocks/CU (VGPR-bound), 16 waves/CU

    const int t    = threadIdx.x;
    const int wid  = t >> 6;                // 0..7
    const int lane = t & 63;
    const int rg   = blockIdx.x % RG;
    const int js   = blockIdx.x / RG;
    const int i0   = rg * RB;
    const int jc   = js * JC;
    const int jend = jc + JC;               // chunk boundary (JC*JS == NN exactly)

    // staging / qcompute mapping: wave wid -> (row, colhalf); lanes 0..31 active
    const int srow = wid >> 1;
    const int sch  = (wid & 1) << 7;        // 0 or 128
    const int scol = sch + ((lane & 31) << 2);
    const bool sact = (lane < 32);
    // Phase B mapping: 16 half-waves x 16 j each; d-quad per lane
    const int hw = t >> 5;                  // 0..15
    const int d0 = (t & 31) << 2;

    float th[SS];
#pragma unroll
    for (int s = 0; s < SS; ++s) th[s] = theta[s];

    // DMA tile k: 9 instrs/wave, 512 B each (lanes 0..31), streaming hint.
    auto stage_dma = [&](int k) {
        const int jg = jc + k * JT + scol;
        if (sact && jg < jend) {
            const size_t goff = (size_t)(i0 + srow) * NN + jg;
#pragma unroll
            for (int s = 0; s < SS; ++s)
                gld_lds16_nt(Tm + (size_t)s * NNSQ + goff, &stg[s][srow][sch]);
            gld_lds16_nt(am + goff, &stg[SS][srow][sch]);
        }
    };

    // q for tile k -> qv[n]; reads only own-wave staged (row, colhalf)
    auto qcompute = [&](int k, int n) {
        if (sact) {
            const int jg = jc + k * JT + scol;
            f4 ssum = (*(const f4*)&stg[0][srow][scol]) * th[0];
#pragma unroll
            for (int s = 1; s < SS; ++s)
                ssum += (*(const f4*)&stg[s][srow][scol]) * th[s];
            f4 q = (*(const f4*)&stg[SS][srow][scol]) * ssum;
            if (jg >= jend) q = (f4)(0.0f);  // ragged tile: zero stale cols
            *(f4*)&qv[n][srow][scol] = q;
        }
    };

    f4 acc[RB];
#pragma unroll
    for (int r = 0; r < RB; ++r) acc[r] = (f4)(0.0f);

    // prologue
    stage_dma(0);
    VMCNT0;
    SB0;
    qcompute(0, 0);
    __syncthreads();

#pragma unroll 1
    for (int k = 0; k < TPB; ++k) {
        // ---- x loads for THIS tile: FIRST into the vmcnt FIFO ----
        f4 xv[16];                           // static indexing only
        {
            const int jb = jc + k * JT + (hw << 4);
#pragma unroll
            for (int q = 0; q < 16; ++q) {
                const int j = jb + q;
                xv[q] = (j < jend) ? *(const f4*)(x + (size_t)j * DD + d0)
                                   : (f4)(0.0f);
            }
        }
        SB0;
        // ---- next tile's T/a DMA: LAST into the FIFO (0 registers) ----
        if (k + 1 < TPB) stage_dma(k + 1);
        SB0;

        // ---- Phase B: acc[r] += qv[r][jj] * x[jj][d0..d0+3] ----
        // consuming xv waits vmcnt<=9 at worst -> DMA stays in flight
        const float* qp = &qv[k & 1][0][0];
#pragma unroll
        for (int qc = 0; qc < 4; ++qc) {
#pragma unroll
            for (int r = 0; r < RB; ++r) {
                f4 q4 = *(const f4*)&qp[r * JT + (hw << 4) + (qc << 2)];
                acc[r] += q4.x * xv[qc * 4 + 0];
                acc[r] += q4.y * xv[qc * 4 + 1];
                acc[r] += q4.z * xv[qc * 4 + 2];
                acc[r] += q4.w * xv[qc * 4 + 3];
            }
        }

        if (k + 1 < TPB) {
            VMCNT0;                          // DMA issued ~2000 cyc ago (wall)
            SB0;
            qcompute(k + 1, (k + 1) & 1);    // own-wave -> no pre-barrier
            __syncthreads();                 // publish qv; orders stage reuse
        }
    }

    // ---- epilogue: fold half-wave j-groups, then cross-wave reduce ----
#pragma unroll
    for (int r = 0; r < RB; ++r)
#pragma unroll
        for (int c = 0; c < 4; ++c)
            acc[r][c] += __shfl_xor(acc[r][c], 32);

    __syncthreads();                         // loop done; stage dead -> alias
    float* red = (float*)&stg[0][0][0];      // 7 waves * 4 rows * 128 d = 14,336 B
    if (wid > 0 && lane < 32) {
#pragma unroll
        for (int r = 0; r < RB; ++r)
            *(f4*)&red[((wid - 1) * RB + r) * DD + d0] = acc[r];
    }
    __syncthreads();
    if (wid == 0 && lane < 32) {
#pragma unroll
        for (int r = 0; r < RB; ++r) {
            f4 v = acc[r];
#pragma unroll
            for (int p = 0; p < 7; ++p)
                v += *(const f4*)&red[(p * RB + r) * DD + d0];
            *(f4*)&ws[(((size_t)js * RG + rg) * RB + r) * DD + d0] = v;
        }
    }
}

// Kernel 2: out[i,:] = PReLU(sum_js partial[js][i,:]) @ W^T + b
__global__ __launch_bounds__(256, 2)
void prelu_linear(const float* __restrict__ alpha,
                  const float* __restrict__ W,
                  const float* __restrict__ b,
                  const float* __restrict__ ws,
                  float* __restrict__ out)
{
    __shared__ float Wt[128 * 129];
    __shared__ float p[16 * 128];
    const int t  = threadIdx.x;
    const int i0 = blockIdx.x * 16;

#pragma unroll
    for (int it = 0; it < 16; ++it) {
        int f  = (it * 256 + t) * 4;
        int d  = f >> 7;
        int kk = f & 127;
        f4 w4 = *(const f4*)(W + f);
        Wt[(kk + 0) * 129 + d] = w4.x;
        Wt[(kk + 1) * 129 + d] = w4.y;
        Wt[(kk + 2) * 129 + d] = w4.z;
        Wt[(kk + 3) * 129 + d] = w4.w;
    }

#pragma unroll
    for (int it = 0; it < 2; ++it) {
        int fi  = it * 256 + t;
        int row = i0 + (fi >> 5);
        int dc  = (fi & 31) << 2;
        if (row < NN) {
            size_t base = (size_t)row * DD + dc;
            f4 v = *(const f4*)(ws + base);
            v += *(const f4*)(ws + base + (size_t)RG * RB * DD);   // 2nd partial
            f4 al = *(const f4*)(alpha + dc);
            f4 pv;
            pv.x = v.x >= 0.f ? v.x : al.x * v.x;
            pv.y = v.y >= 0.f ? v.y : al.y * v.y;
            pv.z = v.z >= 0.f ? v.z : al.z * v.z;
            pv.w = v.w >= 0.f ? v.w : al.w * v.w;
            *(f4*)&p[(row - i0) * 128 + dc] = pv;
        }
    }
    __syncthreads();

    const int d  = t & 127;
    const int rq = t >> 7;
    const float bv = b[d];
    float acc[8];
#pragma unroll
    for (int ri = 0; ri < 8; ++ri) acc[ri] = 0.f;
#pragma unroll 8
    for (int k = 0; k < 128; ++k) {
        float wv = Wt[k * 129 + d];
#pragma unroll
        for (int ri = 0; ri < 8; ++ri)
            acc[ri] += p[(rq * 8 + ri) * 128 + k] * wv;
    }
#pragma unroll
    for (int ri = 0; ri < 8; ++ri) {
        int row = i0 + rq * 8 + ri;
        if (row < NN) out[(size_t)row * DD + d] = acc[ri] + bv;
    }
}

extern "C" void kernel_launch(void* const* d_in, const int* in_sizes, int n_in,
                              void* d_out, int out_size, void* d_ws, size_t ws_size,
                              hipStream_t stream) {
    const float* theta = (const float*)d_in[0];
    const float* T     = (const float*)d_in[1];
    const float* x     = (const float*)d_in[2];
    const float* a     = (const float*)d_in[3];
    const float* alpha = (const float*)d_in[4];
    const float* W     = (const float*)d_in[5];
    const float* b     = (const float*)d_in[6];
    float* out = (float*)d_out;
    float* ws  = (float*)d_ws;

    dim3 g1(RG * JS);                  // 2500 blocks x 512 threads
    diffuse_spmm<<<g1, dim3(512), 0, stream>>>(theta, T, x, a, ws);

    dim3 g2((NN + 15) / 16);           // 313 blocks
    prelu_linear<<<g2, dim3(256), 0, stream>>>(alpha, W, b, ws, out);
}